// Round 1
// baseline (122.929 us; speedup 1.0000x reference)
//
#include <hip/hip_runtime.h>

#define BATCHES 4
#define NPTS    8192
#define ACH     1024   // a-points per block
#define BCH     1024   // b-points per LDS chunk
#define RPT     4      // a-points per thread
#define TPB     256

// For each a-point, min over a chunk of b-points of squared distance,
// using d2 = a2 + (b2 - 2*a.b); track t = b2 - 2*a.b, add a2 at the end.
__global__ __launch_bounds__(TPB) void chamfer_pairmin(
    const float* __restrict__ x, const float* __restrict__ y,
    float* __restrict__ minbuf /* [2][BATCHES][NPTS] */)
{
    const int AC = NPTS / ACH;   // 8
    const int BC = NPTS / BCH;   // 8
    int bid   = blockIdx.x;
    int dir   = bid / (BATCHES * AC * BC);
    int rem   = bid % (BATCHES * AC * BC);
    int batch = rem / (AC * BC);
    int rem2  = rem % (AC * BC);
    int aC    = rem2 / BC;
    int bC    = rem2 % BC;

    const float* Ap = (dir == 0) ? x : y;
    const float* Bp = (dir == 0) ? y : x;
    float* outMin = minbuf + (size_t)dir * BATCHES * NPTS;

    __shared__ float4 sy[BCH];
    const float* bsrc = Bp + ((size_t)batch * NPTS + (size_t)bC * BCH) * 3;
    for (int i = threadIdx.x; i < BCH; i += TPB) {
        float b0 = bsrc[i * 3 + 0];
        float b1 = bsrc[i * 3 + 1];
        float b2 = bsrc[i * 3 + 2];
        sy[i] = make_float4(b0, b1, b2, b0 * b0 + b1 * b1 + b2 * b2);
    }
    __syncthreads();

    float a0[RPT], a1[RPT], a2[RPT], an[RPT], tmin[RPT];
    #pragma unroll
    for (int r = 0; r < RPT; ++r) {
        int ai = aC * ACH + r * TPB + threadIdx.x;
        const float* ap = Ap + ((size_t)batch * NPTS + ai) * 3;
        a0[r] = ap[0]; a1[r] = ap[1]; a2[r] = ap[2];
        an[r] = a0[r] * a0[r] + a1[r] * a1[r] + a2[r] * a2[r];
        tmin[r] = 3.0e38f;
    }

    #pragma unroll 4
    for (int m = 0; m < BCH; ++m) {
        float4 yv = sy[m];   // wave-uniform index -> LDS broadcast, no conflict
        #pragma unroll
        for (int r = 0; r < RPT; ++r) {
            float dot = fmaf(a0[r], yv.x, fmaf(a1[r], yv.y, a2[r] * yv.z));
            float t   = fmaf(dot, -2.0f, yv.w);
            tmin[r]   = fminf(tmin[r], t);
        }
    }

    #pragma unroll
    for (int r = 0; r < RPT; ++r) {
        int ai = aC * ACH + r * TPB + threadIdx.x;
        float d2 = fmaxf(an[r] + tmin[r], 0.0f);   // clamp so int-ordered atomicMin is exact
        atomicMin((int*)&outMin[(size_t)batch * NPTS + ai], __float_as_int(d2));
    }
}

__global__ __launch_bounds__(256) void chamfer_reduce(
    const float* __restrict__ minbuf, float* __restrict__ out)
{
    const int total = 2 * BATCHES * NPTS;
    double s = 0.0;
    for (int i = threadIdx.x; i < total; i += 256) s += (double)minbuf[i];
    #pragma unroll
    for (int off = 32; off > 0; off >>= 1) s += __shfl_down(s, off, 64);
    __shared__ double sd[4];
    int wid = threadIdx.x >> 6;
    if ((threadIdx.x & 63) == 0) sd[wid] = s;
    __syncthreads();
    if (threadIdx.x == 0) {
        double tot = sd[0] + sd[1] + sd[2] + sd[3];
        out[0] = (float)(tot / (double)(BATCHES * NPTS));
    }
}

extern "C" void kernel_launch(void* const* d_in, const int* in_sizes, int n_in,
                              void* d_out, int out_size, void* d_ws, size_t ws_size,
                              hipStream_t stream)
{
    const float* x = (const float*)d_in[0];
    const float* y = (const float*)d_in[1];
    float* out    = (float*)d_out;
    float* minbuf = (float*)d_ws;   // 2*4*8192 floats = 256 KB

    // init mins to 0x7F7F7F7F = 3.3961e38f (> any real d2, < tmin init + an)
    hipMemsetAsync(minbuf, 0x7F, (size_t)2 * BATCHES * NPTS * sizeof(float), stream);

    int nblocks = 2 * BATCHES * (NPTS / ACH) * (NPTS / BCH);   // 512
    chamfer_pairmin<<<nblocks, TPB, 0, stream>>>(x, y, minbuf);
    chamfer_reduce<<<1, 256, 0, stream>>>(minbuf, out);
}

// Round 2
// 55.921 us; speedup vs baseline: 2.1983x; 2.1983x over previous
//
#include <hip/hip_runtime.h>

#define BATCHES 4
#define NPTS    8192
#define ACH     1024   // a-points per block
#define BCH     1024   // b-points per LDS chunk
#define RPT     4      // a-points per thread
#define TPB     256

// For each a-point, min over a chunk of b-points of squared distance.
// LDS holds (-2*b0, -2*b1, -2*b2, |b|^2) so per pair:
//   t = fma(-2b0,a0, fma(-2b1,a1, fma(-2b2,a2, |b|^2)))   (3 FMA)
//   d2 = |a|^2 + min_m t                                   (added once at end)
__global__ __launch_bounds__(TPB) void chamfer_pairmin(
    const float* __restrict__ x, const float* __restrict__ y,
    float* __restrict__ minbuf /* [2][BATCHES][NPTS] */)
{
    const int AC = NPTS / ACH;   // 8
    const int BC = NPTS / BCH;   // 8
    int bid   = blockIdx.x;
    int dir   = bid / (BATCHES * AC * BC);
    int rem   = bid % (BATCHES * AC * BC);
    int batch = rem / (AC * BC);
    int rem2  = rem % (AC * BC);
    int aC    = rem2 / BC;
    int bC    = rem2 % BC;

    const float* Ap = (dir == 0) ? x : y;
    const float* Bp = (dir == 0) ? y : x;
    float* outMin = minbuf + (size_t)dir * BATCHES * NPTS;

    __shared__ float4 sy[BCH];
    const float* bsrc = Bp + ((size_t)batch * NPTS + (size_t)bC * BCH) * 3;
    for (int i = threadIdx.x; i < BCH; i += TPB) {
        float b0 = bsrc[i * 3 + 0];
        float b1 = bsrc[i * 3 + 1];
        float b2 = bsrc[i * 3 + 2];
        sy[i] = make_float4(-2.0f * b0, -2.0f * b1, -2.0f * b2,
                            b0 * b0 + b1 * b1 + b2 * b2);
    }
    __syncthreads();

    float a0[RPT], a1[RPT], a2[RPT], an[RPT], tmin[RPT];
    #pragma unroll
    for (int r = 0; r < RPT; ++r) {
        int ai = aC * ACH + r * TPB + threadIdx.x;
        const float* ap = Ap + ((size_t)batch * NPTS + ai) * 3;
        a0[r] = ap[0]; a1[r] = ap[1]; a2[r] = ap[2];
        an[r] = a0[r] * a0[r] + a1[r] * a1[r] + a2[r] * a2[r];
        tmin[r] = 3.0e38f;
    }

    #pragma unroll 4
    for (int m = 0; m < BCH; m += 2) {
        float4 y0 = sy[m];       // wave-uniform -> LDS broadcast, no conflict
        float4 y1 = sy[m + 1];
        #pragma unroll
        for (int r = 0; r < RPT; ++r) {
            float t0 = fmaf(y0.x, a0[r], fmaf(y0.y, a1[r], fmaf(y0.z, a2[r], y0.w)));
            float t1 = fmaf(y1.x, a0[r], fmaf(y1.y, a1[r], fmaf(y1.z, a2[r], y1.w)));
            tmin[r] = fminf(tmin[r], fminf(t0, t1));   // hope: v_min3_f32
        }
    }

    #pragma unroll
    for (int r = 0; r < RPT; ++r) {
        int ai = aC * ACH + r * TPB + threadIdx.x;
        float d2 = fmaxf(an[r] + tmin[r], 0.0f);   // clamp so int-ordered atomicMin is exact
        atomicMin((int*)&outMin[(size_t)batch * NPTS + ai], __float_as_int(d2));
    }
}

// Stage 1: 64 blocks x 256 threads, each thread sums one float4 (fixed order).
__global__ __launch_bounds__(256) void chamfer_reduce1(
    const float* __restrict__ minbuf, double* __restrict__ partials)
{
    int base = blockIdx.x * 1024 + threadIdx.x * 4;
    float4 v = *reinterpret_cast<const float4*>(minbuf + base);
    double s = ((double)v.x + (double)v.y) + ((double)v.z + (double)v.w);
    #pragma unroll
    for (int off = 32; off > 0; off >>= 1) s += __shfl_down(s, off, 64);
    __shared__ double sd[4];
    int wid = threadIdx.x >> 6;
    if ((threadIdx.x & 63) == 0) sd[wid] = s;
    __syncthreads();
    if (threadIdx.x == 0)
        partials[blockIdx.x] = (sd[0] + sd[1]) + (sd[2] + sd[3]);
}

// Stage 2: one wave sums the 64 partials.
__global__ __launch_bounds__(64) void chamfer_reduce2(
    const double* __restrict__ partials, float* __restrict__ out)
{
    double s = partials[threadIdx.x];
    #pragma unroll
    for (int off = 32; off > 0; off >>= 1) s += __shfl_down(s, off, 64);
    if (threadIdx.x == 0)
        out[0] = (float)(s / (double)(BATCHES * NPTS));
}

extern "C" void kernel_launch(void* const* d_in, const int* in_sizes, int n_in,
                              void* d_out, int out_size, void* d_ws, size_t ws_size,
                              hipStream_t stream)
{
    const float* x = (const float*)d_in[0];
    const float* y = (const float*)d_in[1];
    float* out      = (float*)d_out;
    float* minbuf   = (float*)d_ws;                       // 2*4*8192 floats = 256 KB
    double* partials = (double*)((char*)d_ws + (size_t)2 * BATCHES * NPTS * sizeof(float));

    // init mins to 0x7F7F7F7F = 3.3961e38f (> any real d2)
    hipMemsetAsync(minbuf, 0x7F, (size_t)2 * BATCHES * NPTS * sizeof(float), stream);

    int nblocks = 2 * BATCHES * (NPTS / ACH) * (NPTS / BCH);   // 512
    chamfer_pairmin<<<nblocks, TPB, 0, stream>>>(x, y, minbuf);
    chamfer_reduce1<<<64, 256, 0, stream>>>(minbuf, partials);
    chamfer_reduce2<<<1, 64, 0, stream>>>(partials, out);
}

// Round 3
// 53.838 us; speedup vs baseline: 2.2833x; 1.0387x over previous
//
#include <hip/hip_runtime.h>

#define BATCHES 4
#define NPTS    8192
#define ACH     2048   // a-points per block
#define BCH     256    // b-points per LDS chunk
#define RPT     8      // a-points per thread
#define TPB     256

// For each a-point, min over a chunk of b-points of squared distance.
// LDS holds (-2*b0, -2*b1, -2*b2, |b|^2) so per pair:
//   t = fma(-2b0,a0, fma(-2b1,a1, fma(-2b2,a2, |b|^2)))   (3 FMA)
//   tmin = min3(tmin, t0, t1)                              (1/2 op per pair)
//   d2 = |a|^2 + min_m t                                   (added once at end)
__global__ __launch_bounds__(TPB) void chamfer_pairmin(
    const float* __restrict__ x, const float* __restrict__ y,
    float* __restrict__ minbuf /* [2][BATCHES][NPTS] */)
{
    const int AC = NPTS / ACH;   // 4
    const int BC = NPTS / BCH;   // 32
    int bid   = blockIdx.x;
    int dir   = bid / (BATCHES * AC * BC);
    int rem   = bid % (BATCHES * AC * BC);
    int batch = rem / (AC * BC);
    int rem2  = rem % (AC * BC);
    int aC    = rem2 / BC;
    int bC    = rem2 % BC;

    const float* Ap = (dir == 0) ? x : y;
    const float* Bp = (dir == 0) ? y : x;
    float* outMin = minbuf + (size_t)dir * BATCHES * NPTS;

    __shared__ float4 sy[BCH];
    {
        const float* bsrc = Bp + ((size_t)batch * NPTS + (size_t)bC * BCH) * 3;
        int i = threadIdx.x;          // exactly one point per thread
        float b0 = bsrc[i * 3 + 0];
        float b1 = bsrc[i * 3 + 1];
        float b2 = bsrc[i * 3 + 2];
        sy[i] = make_float4(-2.0f * b0, -2.0f * b1, -2.0f * b2,
                            b0 * b0 + b1 * b1 + b2 * b2);
    }
    __syncthreads();

    float a0[RPT], a1[RPT], a2[RPT], an[RPT], tmin[RPT];
    #pragma unroll
    for (int r = 0; r < RPT; ++r) {
        int ai = aC * ACH + r * TPB + threadIdx.x;
        const float* ap = Ap + ((size_t)batch * NPTS + ai) * 3;
        a0[r] = ap[0]; a1[r] = ap[1]; a2[r] = ap[2];
        an[r] = a0[r] * a0[r] + a1[r] * a1[r] + a2[r] * a2[r];
        tmin[r] = 3.0e38f;
    }

    #pragma unroll 2
    for (int m = 0; m < BCH; m += 2) {
        float4 y0 = sy[m];       // wave-uniform -> LDS broadcast, no conflict
        float4 y1 = sy[m + 1];
        #pragma unroll
        for (int r = 0; r < RPT; ++r) {
            float t0 = fmaf(y0.x, a0[r], fmaf(y0.y, a1[r], fmaf(y0.z, a2[r], y0.w)));
            float t1 = fmaf(y1.x, a0[r], fmaf(y1.y, a1[r], fmaf(y1.z, a2[r], y1.w)));
            tmin[r] = fminf(tmin[r], fminf(t0, t1));   // v_min3_f32
        }
    }

    #pragma unroll
    for (int r = 0; r < RPT; ++r) {
        int ai = aC * ACH + r * TPB + threadIdx.x;
        float d2 = fmaxf(an[r] + tmin[r], 0.0f);   // clamp so int-ordered atomicMin is exact
        atomicMin((int*)&outMin[(size_t)batch * NPTS + ai], __float_as_int(d2));
    }
}

// Stage 1: 64 blocks x 256 threads, each thread sums one float4 (fixed order).
__global__ __launch_bounds__(256) void chamfer_reduce1(
    const float* __restrict__ minbuf, double* __restrict__ partials)
{
    int base = blockIdx.x * 1024 + threadIdx.x * 4;
    float4 v = *reinterpret_cast<const float4*>(minbuf + base);
    double s = ((double)v.x + (double)v.y) + ((double)v.z + (double)v.w);
    #pragma unroll
    for (int off = 32; off > 0; off >>= 1) s += __shfl_down(s, off, 64);
    __shared__ double sd[4];
    int wid = threadIdx.x >> 6;
    if ((threadIdx.x & 63) == 0) sd[wid] = s;
    __syncthreads();
    if (threadIdx.x == 0)
        partials[blockIdx.x] = (sd[0] + sd[1]) + (sd[2] + sd[3]);
}

// Stage 2: one wave sums the 64 partials.
__global__ __launch_bounds__(64) void chamfer_reduce2(
    const double* __restrict__ partials, float* __restrict__ out)
{
    double s = partials[threadIdx.x];
    #pragma unroll
    for (int off = 32; off > 0; off >>= 1) s += __shfl_down(s, off, 64);
    if (threadIdx.x == 0)
        out[0] = (float)(s / (double)(BATCHES * NPTS));
}

extern "C" void kernel_launch(void* const* d_in, const int* in_sizes, int n_in,
                              void* d_out, int out_size, void* d_ws, size_t ws_size,
                              hipStream_t stream)
{
    const float* x = (const float*)d_in[0];
    const float* y = (const float*)d_in[1];
    float* out       = (float*)d_out;
    float* minbuf    = (float*)d_ws;                      // 2*4*8192 floats = 256 KB
    double* partials = (double*)((char*)d_ws + (size_t)2 * BATCHES * NPTS * sizeof(float));

    // init mins to 0x7F7F7F7F = 3.3961e38f (> any real d2)
    hipMemsetAsync(minbuf, 0x7F, (size_t)2 * BATCHES * NPTS * sizeof(float), stream);

    int nblocks = 2 * BATCHES * (NPTS / ACH) * (NPTS / BCH);   // 1024
    chamfer_pairmin<<<nblocks, TPB, 0, stream>>>(x, y, minbuf);
    chamfer_reduce1<<<64, 256, 0, stream>>>(minbuf, partials);
    chamfer_reduce2<<<1, 64, 0, stream>>>(partials, out);
}

// Round 4
// 51.344 us; speedup vs baseline: 2.3942x; 1.0486x over previous
//
#include <hip/hip_runtime.h>

#define BATCHES 4
#define NPTS    8192
#define ACH     2048   // a-points per block
#define BCH     256    // b-points per LDS chunk
#define RPT     8      // a-points per thread
#define TPB     256

// d2 = |a|^2 + t,  t = fma(-2b0,a0, fma(-2b1,a1, fma(-2b2,a2, |b|^2)))  (3 FMA/pair)
// min via nested fminf -> v_min3_f32 (0.5 op/pair).
// Register double-buffered LDS reads: while computing on one 4-point set,
// the next 4 points are already loaded (prefetch distance ~112 issue cycles).
__global__ __launch_bounds__(TPB) void chamfer_pairmin(
    const float* __restrict__ x, const float* __restrict__ y,
    float* __restrict__ minbuf /* [2][BATCHES][NPTS] */)
{
    const int AC = NPTS / ACH;   // 4
    const int BC = NPTS / BCH;   // 32
    int bid   = blockIdx.x;
    int dir   = bid / (BATCHES * AC * BC);
    int rem   = bid % (BATCHES * AC * BC);
    int batch = rem / (AC * BC);
    int rem2  = rem % (AC * BC);
    int aC    = rem2 / BC;
    int bC    = rem2 % BC;

    const float* Ap = (dir == 0) ? x : y;
    const float* Bp = (dir == 0) ? y : x;
    float* outMin = minbuf + (size_t)dir * BATCHES * NPTS;

    __shared__ float4 sy[BCH + 4];   // +4 pad: tail prefetch reads are dead but in-bounds
    {
        const float* bsrc = Bp + ((size_t)batch * NPTS + (size_t)bC * BCH) * 3;
        int i = threadIdx.x;          // exactly one point per thread
        float b0 = bsrc[i * 3 + 0];
        float b1 = bsrc[i * 3 + 1];
        float b2 = bsrc[i * 3 + 2];
        sy[i] = make_float4(-2.0f * b0, -2.0f * b1, -2.0f * b2,
                            b0 * b0 + b1 * b1 + b2 * b2);
    }
    __syncthreads();

    float a0[RPT], a1[RPT], a2[RPT], an[RPT], tmin[RPT];
    #pragma unroll
    for (int r = 0; r < RPT; ++r) {
        int ai = aC * ACH + r * TPB + threadIdx.x;
        const float* ap = Ap + ((size_t)batch * NPTS + ai) * 3;
        a0[r] = ap[0]; a1[r] = ap[1]; a2[r] = ap[2];
        an[r] = a0[r] * a0[r] + a1[r] * a1[r] + a2[r] * a2[r];
        tmin[r] = 3.0e38f;
    }

#define CHAMFER_BODY(q0, q1, q2, q3)                                              \
    _Pragma("unroll")                                                             \
    for (int r = 0; r < RPT; ++r) {                                               \
        float t0 = fmaf(q0.x, a0[r], fmaf(q0.y, a1[r], fmaf(q0.z, a2[r], q0.w))); \
        float t1 = fmaf(q1.x, a0[r], fmaf(q1.y, a1[r], fmaf(q1.z, a2[r], q1.w))); \
        float t2 = fmaf(q2.x, a0[r], fmaf(q2.y, a1[r], fmaf(q2.z, a2[r], q2.w))); \
        float t3 = fmaf(q3.x, a0[r], fmaf(q3.y, a1[r], fmaf(q3.z, a2[r], q3.w))); \
        tmin[r] = fminf(fminf(t0, t1), fminf(fminf(t2, t3), tmin[r]));            \
    }

    float4 c0 = sy[0], c1 = sy[1], c2 = sy[2], c3 = sy[3];
    #pragma unroll 1
    for (int m = 0; m < BCH; m += 8) {
        float4 n0 = sy[m + 4], n1 = sy[m + 5], n2 = sy[m + 6], n3 = sy[m + 7];
        CHAMFER_BODY(c0, c1, c2, c3)
        c0 = sy[m + 8]; c1 = sy[m + 9]; c2 = sy[m + 10]; c3 = sy[m + 11];
        CHAMFER_BODY(n0, n1, n2, n3)
    }
#undef CHAMFER_BODY

    #pragma unroll
    for (int r = 0; r < RPT; ++r) {
        int ai = aC * ACH + r * TPB + threadIdx.x;
        float d2 = fmaxf(an[r] + tmin[r], 0.0f);   // clamp so int-ordered atomicMin is exact
        atomicMin((int*)&outMin[(size_t)batch * NPTS + ai], __float_as_int(d2));
    }
}

// Stage 1: 64 blocks x 256 threads, each thread sums one float4 (fixed order).
__global__ __launch_bounds__(256) void chamfer_reduce1(
    const float* __restrict__ minbuf, double* __restrict__ partials)
{
    int base = blockIdx.x * 1024 + threadIdx.x * 4;
    float4 v = *reinterpret_cast<const float4*>(minbuf + base);
    double s = ((double)v.x + (double)v.y) + ((double)v.z + (double)v.w);
    #pragma unroll
    for (int off = 32; off > 0; off >>= 1) s += __shfl_down(s, off, 64);
    __shared__ double sd[4];
    int wid = threadIdx.x >> 6;
    if ((threadIdx.x & 63) == 0) sd[wid] = s;
    __syncthreads();
    if (threadIdx.x == 0)
        partials[blockIdx.x] = (sd[0] + sd[1]) + (sd[2] + sd[3]);
}

// Stage 2: one wave sums the 64 partials.
__global__ __launch_bounds__(64) void chamfer_reduce2(
    const double* __restrict__ partials, float* __restrict__ out)
{
    double s = partials[threadIdx.x];
    #pragma unroll
    for (int off = 32; off > 0; off >>= 1) s += __shfl_down(s, off, 64);
    if (threadIdx.x == 0)
        out[0] = (float)(s / (double)(BATCHES * NPTS));
}

extern "C" void kernel_launch(void* const* d_in, const int* in_sizes, int n_in,
                              void* d_out, int out_size, void* d_ws, size_t ws_size,
                              hipStream_t stream)
{
    const float* x = (const float*)d_in[0];
    const float* y = (const float*)d_in[1];
    float* out       = (float*)d_out;
    float* minbuf    = (float*)d_ws;                      // 2*4*8192 floats = 256 KB
    double* partials = (double*)((char*)d_ws + (size_t)2 * BATCHES * NPTS * sizeof(float));

    // init mins to 0x7F7F7F7F = 3.3961e38f (> any real d2)
    hipMemsetAsync(minbuf, 0x7F, (size_t)2 * BATCHES * NPTS * sizeof(float), stream);

    int nblocks = 2 * BATCHES * (NPTS / ACH) * (NPTS / BCH);   // 1024
    chamfer_pairmin<<<nblocks, TPB, 0, stream>>>(x, y, minbuf);
    chamfer_reduce1<<<64, 256, 0, stream>>>(minbuf, partials);
    chamfer_reduce2<<<1, 64, 0, stream>>>(partials, out);
}